// Round 9
// baseline (272.914 us; speedup 1.0000x reference)
//
#include <hip/hip_runtime.h>
#include <cstddef>
#include <cstdint>

#define Tn 52
#define Fn 64
#define Hn 32
#define Bn 8192
#define XHAT_ELEMS (Bn * Tn * Fn)   // fp32 elems of x_hat; xs1 bf16 plane fits in half
#define L2E 1.44269504088896340736f

typedef __attribute__((ext_vector_type(8))) short bf8v;   // 8 bf16 (4 VGPRs)
typedef __attribute__((ext_vector_type(4))) float f4v;    // 4 fp32 accum

__device__ __forceinline__ f4v mfma_bf16(bf8v a, bf8v b, f4v c) {
    return __builtin_amdgcn_mfma_f32_16x16x32_bf16(a, b, c, 0, 0, 0);
}

// RNE round to bf16
__device__ __forceinline__ unsigned short rne_bf16(float v) {
    unsigned b = __float_as_uint(v);
    unsigned r = ((b >> 16) & 1u) + 0x7FFFu;
    return (unsigned short)((b + r) >> 16);
}

__device__ __forceinline__ bf8v rne8(float4 a, float4 b) {
    float v[8] = {a.x, a.y, a.z, a.w, b.x, b.y, b.z, b.w};
    bf8v r;
#pragma unroll
    for (int j = 0; j < 8; ++j) r[j] = (short)rne_bf16(v[j]);
    return r;
}

// barrier WITHOUT vmcnt drain and WITHOUT sched pins: LDS ops are
// compiler-visible, so lgkmcnt(0)+s_barrier is sufficient; the scheduler may
// hoist independent register work across to fill stalls.
__device__ __forceinline__ void lds_barrier() {
    asm volatile("s_waitcnt lgkmcnt(0)" ::: "memory");
    __builtin_amdgcn_s_barrier();
}

// Gates pre-scaled by log2e (g-gate by 2*log2e). One rcp for c2, one for h.
__device__ __forceinline__ float lstm_one(float aI, float aF, float aG, float aO, float& cst) {
    float ei = exp2f(fminf(40.f, -aI));
    float ef = exp2f(fminf(40.f, -aF));
    float eg = exp2f(fminf(40.f, -aG));
    float eo = exp2f(fminf(40.f, -aO));
    float p   = (1.f + ei) * (1.f + eg);
    float num = cst * p + (1.f - eg) * (1.f + ef);
    float den = (1.f + ef) * p;
    float c2  = num * __builtin_amdgcn_rcpf(den);
    cst = c2;
    float e2 = exp2f(fminf(40.f, -2.f * L2E * c2));
    return (1.f - e2) * __builtin_amdgcn_rcpf((1.f + eo) * (1.f + e2));
}

// pin the 12 weight fragments live across the loop (defeats remat/reload)
#define PINW(W)                                                               \
    asm volatile("" : "+v"(W[0][0]), "+v"(W[0][1]), "+v"(W[0][2]),            \
                      "+v"(W[1][0]), "+v"(W[1][1]), "+v"(W[1][2]));           \
    asm volatile("" : "+v"(W[2][0]), "+v"(W[2][1]), "+v"(W[2][2]),            \
                      "+v"(W[3][0]), "+v"(W[3][1]), "+v"(W[3][2]));

// ---------------------------------------------------------------------------
// Prep: weights -> fragment-ordered RNE bf16, pre-scaled by log2e
// (g-gate rows by 2*log2e). [grp][cell(4)][nt(8)][ki(3)][lane(64)][j(8)]
//   gate = nt*16 + (lane&15); k = ki*32 + (lane>>4)*8 + j
// ---------------------------------------------------------------------------
__global__ void prep_kernel(const float* __restrict__ eWih, const float* __restrict__ eWhh,
                            const float* __restrict__ dWih, const float* __restrict__ dWhh,
                            unsigned short* __restrict__ ws)
{
    int fid = blockIdx.x * 256 + threadIdx.x;
    if (fid >= 12288) return;
    int lane = fid & 63;
    int ki   = (fid >> 6) % 3;
    int nt   = (fid / 192) & 7;
    int cell = (fid / 1536) & 3;
    int grp  = fid / 6144;
    const float* Wih = grp ? dWih : eWih;
    const float* Whh = grp ? dWhh : eWhh;
    int gate = nt * 16 + (lane & 15);
    float scale = ((gate >> 5) == 2) ? 2.f * L2E : L2E;
    int k0 = ki * 32 + (lane >> 4) * 8;
    size_t base = (size_t)grp * 98304 + (size_t)cell * 12288 + nt * 1536 + ki * 512 + lane * 8;
#pragma unroll
    for (int j = 0; j < 8; ++j) {
        int k = k0 + j;
        float v = (k < 64) ? Wih[(size_t)cell * 8192 + gate * 64 + k]
                           : Whh[(size_t)cell * 4096 + gate * 32 + (k - 64)];
        ws[base + j] = rne_bf16(v * scale);
    }
}

// ---------------------------------------------------------------------------
// Encoder layer: block = 128 thr (2 waves = q-halves), 16 rows, ONE direction
// (blockIdx.y). grid (512,2) -> 4 independent barrier domains per CU.
// x-part of t+1 hoisted before the barrier; t-loop unrolled x2.
// ---------------------------------------------------------------------------
template<int IS_L0>
__global__ __launch_bounds__(128, 2)
void enc_kernel(const float* __restrict__ X, const unsigned short* __restrict__ Xh,
                const float* __restrict__ h0, const float* __restrict__ c0,
                const unsigned short* __restrict__ Whi, const float* __restrict__ bias,
                int layer, unsigned short* __restrict__ outh, float* __restrict__ z)
{
    __shared__ __align__(16) unsigned short Hsh[2][16][40];   // [parity][row][unit]
    const int tid = threadIdx.x, q = tid >> 6, lane = tid & 63;
    const int a = lane & 15, kb = lane >> 4;
    const int u = q * 16 + a;
    const int row0 = blockIdx.x * 16;
    const int d = blockIdx.y;
    const int ci = 2 * layer + d;

    bf8v WH[4][3];   // 12 frags = 48 VGPR, pinned
#pragma unroll
    for (int g = 0; g < 4; ++g)
#pragma unroll
        for (int ki = 0; ki < 3; ++ki)
            WH[g][ki] = *(const bf8v*)(Whi + (size_t)ci * 12288 + (2 * g + q) * 1536
                                       + ki * 512 + lane * 8);
    f4v bC[4];       // bias splat as MFMA C-operand
#pragma unroll
    for (int g = 0; g < 4; ++g) {
        float bv = bias[ci * 128 + g * 32 + u] * ((g == 2) ? 2.f * L2E : L2E);
        bC[g] = (f4v){bv, bv, bv, bv};
    }
    float cst[4], hfin[4];
#pragma unroll
    for (int j = 0; j < 4; ++j)
        cst[j] = c0[((size_t)ci * Bn + row0 + 4 * kb + j) * Hn + u];

    {   // h0 -> parity 1 (t=0 reads par^1 = 1): 16x32 / 128 thr = 4 each
        int rr = tid >> 3, u4 = (tid & 7) * 4;
        const float* src = h0 + ((size_t)ci * Bn + row0 + rr) * Hn + u4;
#pragma unroll
        for (int e = 0; e < 4; ++e)
            Hsh[1][rr][u4 + e] = rne_bf16(src[e]);
    }
    __syncthreads();

    const int grow = row0 + a;   // this lane's A-fragment row
    float4 p0, p1, p2, p3; bf8v ph0, ph1;
    f4v acc[4];
    {   // t = 0: x-part into acc; prefetch t = 1
        int tt = d ? (Tn - 1) : 0;
        bf8v xf0, xf1;
        if (IS_L0) {
            const float* sp = X + ((size_t)grow * Tn + tt) * Fn;
            xf0 = rne8(*(const float4*)(sp + kb * 8), *(const float4*)(sp + kb * 8 + 4));
            xf1 = rne8(*(const float4*)(sp + 32 + kb * 8), *(const float4*)(sp + 32 + kb * 8 + 4));
        } else {
            size_t so = ((size_t)tt * Bn + grow) * Fn + kb * 8;
            xf0 = *(const bf8v*)(Xh + so);
            xf1 = *(const bf8v*)(Xh + so + 32);
        }
#pragma unroll
        for (int g = 0; g < 4; ++g)
            acc[g] = mfma_bf16(xf1, WH[g][1], mfma_bf16(xf0, WH[g][0], bC[g]));
        int tt1 = d ? (Tn - 2) : 1;
        if (IS_L0) {
            const float* sp = X + ((size_t)grow * Tn + tt1) * Fn;
            p0 = *(const float4*)(sp + kb * 8);      p1 = *(const float4*)(sp + kb * 8 + 4);
            p2 = *(const float4*)(sp + 32 + kb * 8); p3 = *(const float4*)(sp + 32 + kb * 8 + 4);
        } else {
            size_t so = ((size_t)tt1 * Bn + grow) * Fn + kb * 8;
            ph0 = *(const bf8v*)(Xh + so);
            ph1 = *(const bf8v*)(Xh + so + 32);
        }
    }

    auto step = [&](int t, int par) {
        PINW(WH);
        // post-barrier critical path: h-read -> 4 MFMA -> lstm -> write
        bf8v hh = *(const bf8v*)&Hsh[par ^ 1][a][kb * 8];
#pragma unroll
        for (int g = 0; g < 4; ++g) acc[g] = mfma_bf16(hh, WH[g][2], acc[g]);
        int tp = d ? (Tn - 1 - t) : t;
#pragma unroll
        for (int j = 0; j < 4; ++j) {
            float hv = lstm_one(acc[0][j], acc[1][j], acc[2][j], acc[3][j], cst[j]);
            hfin[j] = hv;
            unsigned short hp = rne_bf16(hv);
            Hsh[par][4 * kb + j][u] = hp;
            if (IS_L0)
                outh[((size_t)tp * Bn + row0 + 4 * kb + j) * Fn + d * 32 + u] = hp;
        }
        // pre-barrier: x-part of t+1 + prefetch t+2 (independent of h)
        bf8v xf0, xf1;
        if (IS_L0) { xf0 = rne8(p0, p1); xf1 = rne8(p2, p3); }
        else       { xf0 = ph0; xf1 = ph1; }
#pragma unroll
        for (int g = 0; g < 4; ++g)
            acc[g] = mfma_bf16(xf1, WH[g][1], mfma_bf16(xf0, WH[g][0], bC[g]));
        int ts = (t + 2 < Tn) ? t + 2 : Tn - 1;
        int tt = d ? (Tn - 1 - ts) : ts;
        if (IS_L0) {
            const float* sp = X + ((size_t)grow * Tn + tt) * Fn;
            p0 = *(const float4*)(sp + kb * 8);      p1 = *(const float4*)(sp + kb * 8 + 4);
            p2 = *(const float4*)(sp + 32 + kb * 8); p3 = *(const float4*)(sp + 32 + kb * 8 + 4);
        } else {
            size_t so = ((size_t)tt * Bn + grow) * Fn + kb * 8;
            ph0 = *(const bf8v*)(Xh + so);
            ph1 = *(const bf8v*)(Xh + so + 32);
        }
        lds_barrier();
    };
    for (int it = 0; it < Tn / 2; ++it) {   // unrolled x2: compile-time parity
        step(2 * it, 0);
        step(2 * it + 1, 1);
    }
#pragma unroll
    for (int j = 0; j < 4; ++j) {
        size_t zr = (size_t)(row0 + 4 * kb + j) * 256;
        z[zr + ci * 32 + u]       = hfin[j];
        z[zr + 128 + ci * 32 + u] = cst[j];
    }
}

// ---------------------------------------------------------------------------
// Decoder: block = 512 thr (8 waves: P x cell x q-half), 32 rows = 2 groups,
// grid 256. Slot pipeline: A (cells 0,1) on group g, B (cells 2,3) on g^1.
// h-part of next slot hoisted pre-barrier; t-loop unrolled x2 (static parity);
// setprio(1) around MFMA clusters (A/B waves are role-split).
// ---------------------------------------------------------------------------
__global__ __launch_bounds__(512, 2)
void dec_kernel(const unsigned short* __restrict__ Whi, const float* __restrict__ bias,
                const float* __restrict__ z, float* __restrict__ xhat)
{
    __shared__ __align__(16) unsigned short Ysh[2][2][16][72];      // [grp][par][row][feat]
    __shared__ __align__(16) unsigned short Msh[2][16][72];         // [grp][row][feat]
    __shared__ __align__(16) unsigned short Hsh[4][2][2][16][40];   // [cell][grp][par][row][unit]

    const int tid = threadIdx.x, w = tid >> 6, lane = tid & 63;
    const int P = w >> 2, cl = (w >> 1) & 1, q = w & 1;
    const int cell = P * 2 + cl;
    const int a = lane & 15, kb = lane >> 4, u = q * 16 + a;
    const int row0 = blockIdx.x * 32;

    bf8v WH[4][3];   // 12 frags = 48 VGPR, pinned
#pragma unroll
    for (int g = 0; g < 4; ++g)
#pragma unroll
        for (int ki = 0; ki < 3; ++ki)
            WH[g][ki] = *(const bf8v*)(Whi + (size_t)cell * 12288 + (2 * g + q) * 1536
                                       + ki * 512 + lane * 8);
    f4v bC[4];
#pragma unroll
    for (int g = 0; g < 4; ++g) {
        float bv = bias[cell * 128 + g * 32 + u] * ((g == 2) ? 2.f * L2E : L2E);
        bC[g] = (f4v){bv, bv, bv, bv};
    }

    float cst[2][4];   // [group][j]
#pragma unroll
    for (int G = 0; G < 2; ++G)
#pragma unroll
        for (int j = 0; j < 4; ++j)
            cst[G][j] = z[(size_t)(row0 + G * 16 + 4 * kb + j) * 256 + 128 + cell * 32 + u];

    {   // h-init -> parity-1: 4 cells x 32 rows x 32 units / 512 thr = 8 each
        int ct = tid >> 7, rem = tid & 127, rr = rem >> 2, u8 = (rem & 3) * 8;
        const float* src = z + (size_t)(row0 + rr) * 256 + ct * 32 + u8;
#pragma unroll
        for (int e = 0; e < 8; ++e)
            Hsh[ct][rr >> 4][1][rr & 15][u8 + e] = rne_bf16(src[e]);
    }
    __syncthreads();

    f4v accp[4];
    // h-part precompute for the wave's NEXT work item (wave-private h);
    // bias enters here as the C-operand.
    auto hpart = [&](int G, int rpar) {
        bf8v hh = *(const bf8v*)&Hsh[cell][G][rpar][a][kb * 8];
        __builtin_amdgcn_s_setprio(1);
#pragma unroll
        for (int g = 0; g < 4; ++g) accp[g] = mfma_bf16(hh, WH[g][2], bC[g]);
        __builtin_amdgcn_s_setprio(0);
    };
    // post-barrier finish: V-read -> 8 MFMA -> lstm -> writes. par == t&1.
    auto finish = [&](int G, int t, int par, bool isA, bool hasV) {
        if (hasV) {
            const unsigned short (*Vh)[72] = isA ? Ysh[G][par ^ 1] : Msh[G];
            bf8v vh0 = *(const bf8v*)&Vh[a][kb * 8];
            bf8v vh1 = *(const bf8v*)&Vh[a][32 + kb * 8];
            __builtin_amdgcn_s_setprio(1);
#pragma unroll
            for (int g = 0; g < 4; ++g) {
                accp[g] = mfma_bf16(vh0, WH[g][0], accp[g]);
                accp[g] = mfma_bf16(vh1, WH[g][1], accp[g]);
            }
            __builtin_amdgcn_s_setprio(0);
        }
#pragma unroll
        for (int j = 0; j < 4; ++j) {
            float hv = lstm_one(accp[0][j], accp[1][j], accp[2][j], accp[3][j], cst[G][j]);
            unsigned short hp = rne_bf16(hv);
            int r = 4 * kb + j;
            Hsh[cell][G][par][r][u] = hp;
            if (isA) {
                Msh[G][r][cl * 32 + u] = hp;
            } else {
                Ysh[G][par][r][cl * 32 + u] = hp;
                xhat[((size_t)(row0 + G * 16 + r) * Tn + t) * Fn + cl * 32 + u] = hv;
            }
        }
    };

    hpart(0, 1);   // prologue: both A and B start on (G0, t=0)
    for (int it = 0; it < Tn / 2; ++it) {
        const int t0 = 2 * it, t1 = t0 + 1;
        const bool nz = (it > 0);
        PINW(WH);
        // ---- t0 (par 0) ---- slot even: A(G0,t0), B(G1,t0-1)
        if (P == 0) { finish(0, t0, 0, true, nz);            hpart(1, 1); }
        else        { if (nz) finish(1, t0 - 1, 1, false, true); hpart(0, 1); }
        lds_barrier();
        //                      slot odd: A(G1,t0), B(G0,t0)
        if (P == 0) { finish(1, t0, 0, true, nz);            hpart(0, 0); }
        else        { finish(0, t0, 0, false, true);         hpart(1, 1); }
        lds_barrier();
        PINW(WH);
        // ---- t1 (par 1) ---- slot even: A(G0,t1), B(G1,t0)
        if (P == 0) { finish(0, t1, 1, true, true);          hpart(1, 0); }
        else        { finish(1, t0, 0, false, true);         hpart(0, 0); }
        lds_barrier();
        //                      slot odd: A(G1,t1), B(G0,t1)
        if (P == 0) { finish(1, t1, 1, true, true);          hpart(0, 1); }
        else        { finish(0, t1, 1, false, true);         hpart(1, 0); }
        lds_barrier();
    }
    if (P == 1) finish(1, Tn - 1, 1, false, true);   // epilogue: G1 last step
}

extern "C" void kernel_launch(void* const* d_in, const int* in_sizes, int n_in,
                              void* d_out, int out_size, void* d_ws, size_t ws_size,
                              hipStream_t stream) {
    const float* x    = (const float*)d_in[0];
    const float* h0   = (const float*)d_in[1];
    const float* c0   = (const float*)d_in[2];
    const float* eWih = (const float*)d_in[3];
    const float* eWhh = (const float*)d_in[4];
    const float* eb   = (const float*)d_in[5];
    const float* dWih = (const float*)d_in[6];
    const float* dWhh = (const float*)d_in[7];
    const float* db   = (const float*)d_in[8];

    float* out = (float*)d_out;
    unsigned short* xs1h = (unsigned short*)d_out;          // [T,B,64] bf16 plane
    float* zb = out + (size_t)XHAT_ELEMS;                   // [B,256] latent
    unsigned short* wsb = (unsigned short*)d_ws;            // weight fragments

    hipLaunchKernelGGL(prep_kernel, dim3(48), dim3(256), 0, stream,
                       eWih, eWhh, dWih, dWhh, wsb);
    // encoder layer 0: x -> xs1 plane + z slots 0,1
    hipLaunchKernelGGL((enc_kernel<1>), dim3(Bn / 16, 2), dim3(128), 0, stream,
                       x, (const unsigned short*)nullptr,
                       h0, c0, wsb, eb, 0, xs1h, zb);
    // encoder layer 1: xs1 plane -> z slots 2,3
    hipLaunchKernelGGL((enc_kernel<0>), dim3(Bn / 16, 2), dim3(128), 0, stream,
                       (const float*)nullptr, xs1h,
                       h0, c0, wsb, eb, 1, (unsigned short*)nullptr, zb);
    // decoder: z -> x_hat (overwrites xs1 region)
    hipLaunchKernelGGL(dec_kernel, dim3(Bn / 32), dim3(512), 0, stream,
                       wsb + 98304, db, zb, out);
}